// Round 2
// baseline (6362.394 us; speedup 1.0000x reference)
//
#include <hip/hip_runtime.h>
#include <hip/hip_bf16.h>
#include <math.h>

typedef __hip_bfloat16 bf16;

#define D_MODEL   2048
#define D_INNER   4096
#define NHEADS    64
#define DSTATE    64
#define D_XB      1024
#define XB_HEADS  16
#define REP       4
#define DCONV     4
#define CHUNK     128
#define SEQLEN    4096
#define NCHUNK    (SEQLEN / CHUNK)                 // 32
#define D_IN_PROJ (2*D_INNER + 2*D_XB + NHEADS)    // 10304
#define CONV_DIM  (D_INNER + 2*D_XB)               // 6144
#define EPS       1e-5f

// ---------------- workspace layout (bytes) ----------------
#define Z_BYTES    ((size_t)SEQLEN * D_INNER * 2)                   // 33,554,432
#define RAW_BYTES  ((size_t)SEQLEN * CONV_DIM * 2)                  // 50,331,648
#define CONV_BYTES ((size_t)SEQLEN * CONV_DIM * 2)                  // 50,331,648
#define DTP_BYTES  ((size_t)SEQLEN * NHEADS * 4)                    //  1,048,576
#define S_BYTES    ((size_t)NCHUNK * NHEADS * DSTATE * DSTATE * 4)  // 33,554,432
#define CDEC_BYTES ((size_t)NCHUNK * NHEADS * 4)                    //      8,192
#define WS_BYTES   (Z_BYTES + RAW_BYTES + CONV_BYTES + DTP_BYTES + S_BYTES + CDEC_BYTES)
// total = 168,828,928 B  (~161 MB)

// ---------------- diagnostic fill (only if ws too small) ----------------
__global__ void fill_kernel(float* p, size_t n, float v) {
  size_t i = (size_t)blockIdx.x * blockDim.x + threadIdx.x;
  if (i < n) p[i] = v;
}

// ---------------- GEMM1: zxbcdt = u @ W_in, split epilogue ----------------
// A f32 (4096x2048), B f32 (2048x10304). Writes z bf16, raw-xBC bf16, dt f32.
__global__ __launch_bounds__(256) void gemm1_split(
    const float* __restrict__ A, const float* __restrict__ B,
    bf16* __restrict__ z, bf16* __restrict__ raw, float* __restrict__ dtraw) {
  __shared__ float As[16][65];
  __shared__ float Bs[16][65];
  const int tid = threadIdx.x;
  const int tx = tid & 15, ty = tid >> 4;
  const int rowBase = blockIdx.y * 64;
  const int colBase = blockIdx.x * 64;
  float acc[4][4] = {};
  for (int k0 = 0; k0 < D_MODEL; k0 += 16) {
    for (int i = tid; i < 64 * 16; i += 256) {
      int r = i >> 4, c = i & 15;
      As[c][r] = A[(size_t)(rowBase + r) * D_MODEL + k0 + c];
    }
    for (int i = tid; i < 16 * 64; i += 256) {
      int r = i >> 6, c = i & 63;
      Bs[r][c] = B[(size_t)(k0 + r) * D_IN_PROJ + colBase + c];
    }
    __syncthreads();
#pragma unroll
    for (int kk = 0; kk < 16; ++kk) {
      float a[4], b[4];
#pragma unroll
      for (int i = 0; i < 4; ++i) a[i] = As[kk][ty * 4 + i];
#pragma unroll
      for (int j = 0; j < 4; ++j) b[j] = Bs[kk][tx * 4 + j];
#pragma unroll
      for (int i = 0; i < 4; ++i)
#pragma unroll
        for (int j = 0; j < 4; ++j) acc[i][j] += a[i] * b[j];
    }
    __syncthreads();
  }
#pragma unroll
  for (int i = 0; i < 4; ++i) {
    int row = rowBase + ty * 4 + i;
#pragma unroll
    for (int j = 0; j < 4; ++j) {
      int col = colBase + tx * 4 + j;
      float v = acc[i][j];
      if (col < D_INNER) {
        z[(size_t)row * D_INNER + col] = __float2bfloat16(v);
      } else if (col < D_INNER + CONV_DIM) {
        raw[(size_t)row * CONV_DIM + (col - D_INNER)] = __float2bfloat16(v);
      } else {
        dtraw[(size_t)row * NHEADS + (col - D_INNER - CONV_DIM)] = v;
      }
    }
  }
}

// ---------------- GEMM2: out = normed(bf16) @ W_out(f32) ----------------
__global__ __launch_bounds__(256) void gemm2_bf16a(
    const bf16* __restrict__ A, const float* __restrict__ B, float* __restrict__ C) {
  // M=SEQLEN, N=D_MODEL, K=D_INNER
  __shared__ float As[16][65];
  __shared__ float Bs[16][65];
  const int tid = threadIdx.x;
  const int tx = tid & 15, ty = tid >> 4;
  const int rowBase = blockIdx.y * 64;
  const int colBase = blockIdx.x * 64;
  float acc[4][4] = {};
  for (int k0 = 0; k0 < D_INNER; k0 += 16) {
    for (int i = tid; i < 64 * 16; i += 256) {
      int r = i >> 4, c = i & 15;
      As[c][r] = __bfloat162float(A[(size_t)(rowBase + r) * D_INNER + k0 + c]);
    }
    for (int i = tid; i < 16 * 64; i += 256) {
      int r = i >> 6, c = i & 63;
      Bs[r][c] = B[(size_t)(k0 + r) * D_MODEL + colBase + c];
    }
    __syncthreads();
#pragma unroll
    for (int kk = 0; kk < 16; ++kk) {
      float a[4], b[4];
#pragma unroll
      for (int i = 0; i < 4; ++i) a[i] = As[kk][ty * 4 + i];
#pragma unroll
      for (int j = 0; j < 4; ++j) b[j] = Bs[kk][tx * 4 + j];
#pragma unroll
      for (int i = 0; i < 4; ++i)
#pragma unroll
        for (int j = 0; j < 4; ++j) acc[i][j] += a[i] * b[j];
    }
    __syncthreads();
  }
#pragma unroll
  for (int i = 0; i < 4; ++i)
#pragma unroll
    for (int j = 0; j < 4; ++j)
      C[(size_t)(rowBase + ty * 4 + i) * D_MODEL + colBase + tx * 4 + j] = acc[i][j];
}

// ---------------- conv1d (depthwise causal, DCONV=4) + SiLU ----------------
__global__ __launch_bounds__(256) void conv_silu_kernel(
    const bf16* __restrict__ raw, const float* __restrict__ cw,
    const float* __restrict__ cb, bf16* __restrict__ conv) {
  size_t idx = (size_t)blockIdx.x * blockDim.x + threadIdx.x;
  if (idx >= (size_t)SEQLEN * CONV_DIM) return;
  int t = (int)(idx / CONV_DIM);
  int c = (int)(idx % CONV_DIM);
  float acc = cb[c];
#pragma unroll
  for (int k = 0; k < DCONV; ++k) {
    int tt = t - (DCONV - 1) + k;
    if (tt >= 0) acc += __bfloat162float(raw[(size_t)tt * CONV_DIM + c]) * cw[c * DCONV + k];
  }
  float s = acc / (1.f + expf(-acc));
  conv[idx] = __float2bfloat16(s);
}

// ---------------- dt softplus (in-place on raw dt) ----------------
__global__ __launch_bounds__(256) void dt_softplus_kernel(
    float* __restrict__ dtp, const float* __restrict__ dt_bias) {
  int idx = blockIdx.x * blockDim.x + threadIdx.x;  // t*64+h
  if (idx >= SEQLEN * NHEADS) return;
  int h = idx & (NHEADS - 1);
  float x = dtp[idx] + dt_bias[h];
  dtp[idx] = (x > 20.f) ? x : log1pf(expf(x));
}

// ---------------- SSD pass A: per (chunk, head) state S and chunk decay ----------------
// S[n,p] = sum_j B[j,n] * exp(cum_last - cum[j]) * dt[j] * x[j,p]
__global__ __launch_bounds__(256) void ssd_passA(
    const bf16* __restrict__ conv, const float* __restrict__ dtp,
    const float* __restrict__ A_log, float* __restrict__ Sbuf,
    float* __restrict__ cdec) {
  const int chunk = blockIdx.x;
  const int h = blockIdx.y;
  const int g = h >> 2;          // REP=4
  const int tid = threadIdx.x;
  const int t0 = chunk * CHUNK;
  __shared__ float sdt[CHUNK];
  __shared__ float scum[CHUNK];
  __shared__ float sB[32][64];
  __shared__ float sX[32][64];
  if (tid < CHUNK) sdt[tid] = dtp[(size_t)(t0 + tid) * NHEADS + h];
  __syncthreads();
  if (tid == 0) {
    float Ah = -expf(A_log[h]);
    float run = 0.f;
    for (int i = 0; i < CHUNK; ++i) { run += sdt[i] * Ah; scum[i] = run; }
  }
  __syncthreads();
  const float cumlast = scum[CHUNK - 1];
  const int n = tid >> 2;
  const int p0 = (tid & 3) * 16;
  float acc[16] = {};
  for (int jt = 0; jt < CHUNK; jt += 32) {
    for (int i = tid; i < 32 * 64; i += 256) {
      int r = i >> 6, cc = i & 63;
      size_t trow = (size_t)(t0 + jt + r) * CONV_DIM;
      sB[r][cc] = __bfloat162float(conv[trow + D_XB + g * 64 + cc]);
      sX[r][cc] = __bfloat162float(conv[trow + g * 64 + cc]);
    }
    __syncthreads();
#pragma unroll 4
    for (int r = 0; r < 32; ++r) {
      int j = jt + r;
      float w = expf(cumlast - scum[j]) * sdt[j];
      float bw = sB[r][n] * w;
#pragma unroll
      for (int q = 0; q < 16; ++q) acc[q] += bw * sX[r][p0 + q];
    }
    __syncthreads();
  }
  float* Sout = Sbuf + ((size_t)chunk * NHEADS + h) * (DSTATE * DSTATE);
#pragma unroll
  for (int q = 0; q < 16; ++q) Sout[n * 64 + p0 + q] = acc[q];
  if (tid == 0) cdec[chunk * NHEADS + h] = expf(cumlast);
}

// ---------------- SSD pass B: sequential chunk recurrence, IN-PLACE S -> Hprev ----------
__global__ __launch_bounds__(256) void ssd_passB(
    float* __restrict__ Sbuf, const float* __restrict__ cdec) {
  const int h = blockIdx.x;
  const int tid = threadIdx.x;
  float H[16] = {};
  for (int c = 0; c < NCHUNK; ++c) {
    float* Sc = Sbuf + ((size_t)c * NHEADS + h) * (DSTATE * DSTATE);
    float dec = cdec[c * NHEADS + h];
#pragma unroll
    for (int q = 0; q < 16; ++q) {
      int e = q * 256 + tid;
      float s = Sc[e];
      Sc[e] = H[q];                 // Hprev for chunk c = state BEFORE update
      H[q] = dec * H[q] + s;
    }
  }
}

// ---------------- SSD pass C: y = intra + inter + x*D, gate, RMSNorm ----------------
__global__ __launch_bounds__(256) void ssd_passC(
    const bf16* __restrict__ z, const bf16* __restrict__ conv,
    const float* __restrict__ dtp, const float* __restrict__ A_log,
    const float* __restrict__ Dv, const float* __restrict__ nw,
    const float* __restrict__ Hprev, bf16* __restrict__ normed) {
  const int chunk = blockIdx.x;
  const int h = blockIdx.y;
  const int g = h >> 2;
  const int tid = threadIdx.x;
  const int t0 = chunk * CHUNK;
  __shared__ float sdt[CHUNK];
  __shared__ float scum[CHUNK];
  __shared__ float sC[CHUNK][64];     // 32 KB
  __shared__ float sBX[2][32][64];    // 16 KB (aliased as 64x64 for Hprev)
  for (int i = tid; i < CHUNK * 64; i += 256) {
    int r = i >> 6, cc = i & 63;
    sC[r][cc] = __bfloat162float(conv[(size_t)(t0 + r) * CONV_DIM + 2 * D_XB + h * 64 + cc]);
  }
  if (tid < CHUNK) sdt[tid] = dtp[(size_t)(t0 + tid) * NHEADS + h];
  __syncthreads();
  if (tid == 0) {
    float Ah = -expf(A_log[h]);
    float run = 0.f;
    for (int i = 0; i < CHUNK; ++i) { run += sdt[i] * Ah; scum[i] = run; }
  }
  __syncthreads();
  const int row = tid >> 1;            // 0..127
  const int p0 = (tid & 1) * 32;
  const float cum_i = scum[row];
  float acc[32] = {};
  // ---- intra-chunk
  for (int jt = 0; jt < CHUNK; jt += 32) {
    for (int i = tid; i < 32 * 64; i += 256) {
      int r = i >> 6, cc = i & 63;
      size_t trow = (size_t)(t0 + jt + r) * CONV_DIM;
      sBX[0][r][cc] = __bfloat162float(conv[trow + D_XB + g * 64 + cc]);
      sBX[1][r][cc] = __bfloat162float(conv[trow + g * 64 + cc]);
    }
    __syncthreads();
    for (int r = 0; r < 32; ++r) {
      int j = jt + r;
      if (j <= row) {
        float gdot = 0.f;
#pragma unroll 8
        for (int n = 0; n < 64; ++n) gdot += sC[row][n] * sBX[0][r][n];
        float w = expf(cum_i - scum[j]) * sdt[j] * gdot;
#pragma unroll
        for (int q = 0; q < 32; ++q) acc[q] += w * sBX[1][r][p0 + q];
      }
    }
    __syncthreads();
  }
  // ---- inter-chunk: y2[i,p] = exp(cum_i) * sum_n C[i,n] * Hprev[n,p]
  {
    float* sH = &sBX[0][0][0];  // 4096 floats = 64x64
    const float* Hp = Hprev + ((size_t)chunk * NHEADS + h) * (DSTATE * DSTATE);
    for (int i = tid; i < DSTATE * DSTATE; i += 256) sH[i] = Hp[i];
    __syncthreads();
    float ecum = expf(cum_i);
#pragma unroll 8
    for (int n = 0; n < 64; ++n) {
      float cn = sC[row][n] * ecum;
#pragma unroll
      for (int q = 0; q < 32; ++q) acc[q] += cn * sH[n * 64 + p0 + q];
    }
  }
  // ---- epilogue: +x*D, gate silu(z), RMSNorm over p, * norm_weight
  {
    const int t = t0 + row;
    const float Dh = Dv[h];
    float yz[32];
    float sumsq = 0.f;
#pragma unroll
    for (int q = 0; q < 32; ++q) {
      int p = p0 + q;
      float xv = __bfloat162float(conv[(size_t)t * CONV_DIM + g * 64 + p]);
      float zv = __bfloat162float(z[(size_t)t * D_INNER + h * 64 + p]);
      float sz = zv / (1.f + expf(-zv));
      float v = (acc[q] + xv * Dh) * sz;
      yz[q] = v;
      sumsq += v * v;
    }
    sumsq += __shfl_xor(sumsq, 1);
    float rinv = rsqrtf(sumsq * (1.f / 64.f) + EPS);
#pragma unroll
    for (int q = 0; q < 32; ++q) {
      int p = p0 + q;
      normed[(size_t)t * D_INNER + h * 64 + p] = __float2bfloat16(yz[q] * rinv * nw[h * 64 + p]);
    }
  }
}

// ---------------- launch ----------------
extern "C" void kernel_launch(void* const* d_in, const int* in_sizes, int n_in,
                              void* d_out, int out_size, void* d_ws, size_t ws_size,
                              hipStream_t stream) {
  const float* u       = (const float*)d_in[0];
  const float* W_in    = (const float*)d_in[1];
  const float* conv_w  = (const float*)d_in[2];
  const float* conv_b  = (const float*)d_in[3];
  const float* dt_bias = (const float*)d_in[4];
  const float* A_log   = (const float*)d_in[5];
  const float* Dv      = (const float*)d_in[6];
  const float* norm_w  = (const float*)d_in[7];
  const float* W_out   = (const float*)d_in[8];
  float* out = (float*)d_out;

  if (ws_size < WS_BYTES) {
    // diagnostic: unmistakable output signature if workspace is too small
    size_t n = (size_t)out_size;
    fill_kernel<<<(n + 255) / 256, 256, 0, stream>>>(out, n, 1000.0f);
    return;
  }

  char* wsb   = (char*)d_ws;
  bf16* z     = (bf16*)(wsb);
  bf16* raw   = (bf16*)(wsb + Z_BYTES);
  bf16* conv  = (bf16*)(wsb + Z_BYTES + RAW_BYTES);
  float* dtp  = (float*)(wsb + Z_BYTES + RAW_BYTES + CONV_BYTES);
  float* Sbuf = (float*)(wsb + Z_BYTES + RAW_BYTES + CONV_BYTES + DTP_BYTES);
  float* cdec = (float*)(wsb + Z_BYTES + RAW_BYTES + CONV_BYTES + DTP_BYTES + S_BYTES);
  bf16* normed = raw;   // raw xBC is dead after conv; reuse for normed

  // 1) zxbcdt = u @ W_in  (split into z / raw-xBC / dt)
  {
    dim3 grid(D_IN_PROJ / 64, SEQLEN / 64);
    gemm1_split<<<grid, 256, 0, stream>>>(u, W_in, z, raw, dtp);
  }
  // 2) conv + silu
  {
    size_t tot = (size_t)SEQLEN * CONV_DIM;
    conv_silu_kernel<<<(tot + 255) / 256, 256, 0, stream>>>(raw, conv_w, conv_b, conv);
  }
  // 3) dt softplus (in-place)
  dt_softplus_kernel<<<(SEQLEN * NHEADS + 255) / 256, 256, 0, stream>>>(dtp, dt_bias);
  // 4) SSD pass A
  {
    dim3 grid(NCHUNK, NHEADS);
    ssd_passA<<<grid, 256, 0, stream>>>(conv, dtp, A_log, Sbuf, cdec);
  }
  // 5) SSD pass B (sequential scan, in-place S -> Hprev)
  ssd_passB<<<NHEADS, 256, 0, stream>>>(Sbuf, cdec);
  // 6) SSD pass C (+gate+RMSNorm) -> normed (aliases raw)
  {
    dim3 grid(NCHUNK, NHEADS);
    ssd_passC<<<grid, 256, 0, stream>>>(z, conv, dtp, A_log, Dv, norm_w, Sbuf, normed);
  }
  // 7) out = normed @ W_out
  {
    dim3 grid(D_MODEL / 64, SEQLEN / 64);
    gemm2_bf16a<<<grid, 256, 0, stream>>>(normed, W_out, out);
  }
}

// Round 3
// 1387.555 us; speedup vs baseline: 4.5853x; 4.5853x over previous
//
#include <hip/hip_runtime.h>
#include <hip/hip_bf16.h>
#include <math.h>

typedef __hip_bfloat16 bf16;
typedef __attribute__((ext_vector_type(8))) short short8;
typedef __attribute__((ext_vector_type(4))) float f32x4;

#define D_MODEL   2048
#define D_INNER   4096
#define NHEADS    64
#define DSTATE    64
#define D_XB      1024
#define XB_HEADS  16
#define REP       4
#define DCONV     4
#define CHUNK     128
#define SEQLEN    4096
#define NCHUNK    (SEQLEN / CHUNK)                 // 32
#define D_IN_PROJ (2*D_INNER + 2*D_XB + NHEADS)    // 10304
#define NPAD      10368                            // 81*128
#define CONV_DIM  (D_INNER + 2*D_XB)               // 6144
#define EPS       1e-5f

// ---------------- workspace layout (bytes) ----------------
#define Z_BYTES    ((size_t)SEQLEN * D_INNER * 2)                   // 33,554,432
#define RAW_BYTES  ((size_t)SEQLEN * CONV_DIM * 2)                  // 50,331,648
#define DTP_BYTES  ((size_t)SEQLEN * NHEADS * 4)                    //  1,048,576
#define CDEC_BYTES ((size_t)NCHUNK * NHEADS * 4)                    //      8,192
#define CONV_BYTES ((size_t)SEQLEN * CONV_DIM * 2)                  // 50,331,648
#define S_BYTES    ((size_t)NCHUNK * NHEADS * DSTATE * DSTATE * 4)  // 33,554,432
#define U_BYTES    ((size_t)SEQLEN * D_MODEL * 2)                   // 16,777,216
#define WINT_BYTES ((size_t)NPAD * D_MODEL * 2)                     // 42,467,328
#define WOUTT_BYTES ((size_t)D_MODEL * D_INNER * 2)                 // 16,777,216
#define RREG_BYTES (CONV_BYTES + S_BYTES)                           // 83,886,080 (>= U+WINT)
#define WS_BYTES   (Z_BYTES + RAW_BYTES + DTP_BYTES + CDEC_BYTES + RREG_BYTES)
// total = 168,828,928 B (same as round 2, which fit)

__device__ __forceinline__ short f2bf(float f) {
  bf16 h = __float2bfloat16(f);
  return *reinterpret_cast<short*>(&h);
}

__device__ __forceinline__ void gload_lds16(const void* g, void* l) {
  typedef __attribute__((address_space(1))) const unsigned int guint;
  typedef __attribute__((address_space(3))) unsigned int luint;
  __builtin_amdgcn_global_load_lds((guint*)g, (luint*)l, 16, 0, 0);
}

// ---------------- diagnostic fill ----------------
__global__ void fill_kernel(float* p, size_t n, float v) {
  size_t i = (size_t)blockIdx.x * blockDim.x + threadIdx.x;
  if (i < n) p[i] = v;
}

// ---------------- cast f32 -> bf16 (vectorized x4) ----------------
__global__ __launch_bounds__(256) void cast_f32_bf16(
    const float* __restrict__ in, short* __restrict__ out, size_t n4) {
  size_t i = (size_t)blockIdx.x * 256 + threadIdx.x;
  if (i >= n4) return;
  float4 v = ((const float4*)in)[i];
  short4 o;
  o.x = f2bf(v.x); o.y = f2bf(v.y); o.z = f2bf(v.z); o.w = f2bf(v.w);
  ((short4*)out)[i] = o;
}

// ---------------- transpose + cast: in[R][C] f32 -> out[Cpad][R] bf16 ----------------
__global__ __launch_bounds__(256) void transpose_cast(
    const float* __restrict__ in, short* __restrict__ out, int R, int C) {
  __shared__ float tile[32][33];
  const int c0 = blockIdx.x * 32;
  const int r0 = blockIdx.y * 32;
  const int tx = threadIdx.x & 31, ty = threadIdx.x >> 5;  // 32x8
#pragma unroll
  for (int i = 0; i < 4; ++i) {
    int r = ty + i * 8;
    float v = 0.f;
    if (c0 + tx < C) v = in[(size_t)(r0 + r) * C + c0 + tx];
    tile[r][tx] = v;
  }
  __syncthreads();
#pragma unroll
  for (int i = 0; i < 4; ++i) {
    int rr = ty + i * 8;   // output row offset = input col
    out[(size_t)(c0 + rr) * R + r0 + tx] = f2bf(tile[tx][rr]);
  }
}

// ---------------- MFMA GEMM core: 128x128 tile, BK=64, 4 waves (2x2), 16x16x32 bf16 ----
// A: [M][K] bf16 row-major.  Bt: [N][K] bf16 row-major (i.e. B transposed).
__device__ __forceinline__ void mfma_gemm_core(
    const short* __restrict__ A, const short* __restrict__ Bt, int K,
    int rowBase, int colBase, short As[128][64], short Bs[128][64],
    f32x4 acc[4][4]) {
  const int tid = threadIdx.x;
  const int lane = tid & 63;
  const int wid = tid >> 6;
  const int r_sub = lane >> 3;          // 0..7
  const int c8 = (lane & 7) * 8;        // element col of 16B chunk
  const int wr = (wid >> 1) * 64;
  const int wc = (wid & 1) * 64;
  const int fr = lane & 15;
  const int kb = (lane >> 4) * 8;
  for (int k0 = 0; k0 < K; k0 += 64) {
#pragma unroll
    for (int i = 0; i < 4; ++i) {
      int c = i * 4 + wid;              // 16 chunks of 1KB per tile
      int r = c * 8 + r_sub;
      gload_lds16(A + (size_t)(rowBase + r) * K + k0 + c8, &As[r][c8]);
      gload_lds16(Bt + (size_t)(colBase + r) * K + k0 + c8, &Bs[r][c8]);
    }
    __syncthreads();
#pragma unroll
    for (int kk = 0; kk < 2; ++kk) {
      const int ko = kk * 32 + kb;
      short8 a[4], b[4];
#pragma unroll
      for (int m = 0; m < 4; ++m) a[m] = *(const short8*)&As[wr + m * 16 + fr][ko];
#pragma unroll
      for (int n = 0; n < 4; ++n) b[n] = *(const short8*)&Bs[wc + n * 16 + fr][ko];
#pragma unroll
      for (int m = 0; m < 4; ++m)
#pragma unroll
        for (int n = 0; n < 4; ++n)
          acc[m][n] = __builtin_amdgcn_mfma_f32_16x16x32_bf16(a[m], b[n], acc[m][n], 0, 0, 0);
    }
    __syncthreads();
  }
}

// ---------------- GEMM1: zxbcdt = u @ W_in with split epilogue ----------------
__global__ __launch_bounds__(256) void gemm1_mfma(
    const short* __restrict__ A, const short* __restrict__ Bt,
    bf16* __restrict__ z, bf16* __restrict__ raw, float* __restrict__ dtraw) {
  __shared__ short As[128][64];
  __shared__ short Bs[128][64];
  f32x4 acc[4][4] = {};
  const int rowBase = blockIdx.y * 128;
  const int colBase = blockIdx.x * 128;
  mfma_gemm_core(A, Bt, D_MODEL, rowBase, colBase, As, Bs, acc);
  const int lane = threadIdx.x & 63, wid = threadIdx.x >> 6;
  const int wr = (wid >> 1) * 64, wc = (wid & 1) * 64;
  const int r0 = rowBase + wr + (lane >> 4) * 4;
  const int cb = colBase + wc + (lane & 15);
#pragma unroll
  for (int m = 0; m < 4; ++m)
#pragma unroll
    for (int n = 0; n < 4; ++n) {
      int col = cb + n * 16;
#pragma unroll
      for (int j = 0; j < 4; ++j) {
        int row = r0 + m * 16 + j;
        float v = acc[m][n][j];
        if (col < D_INNER) {
          z[(size_t)row * D_INNER + col] = __float2bfloat16(v);
        } else if (col < D_INNER + CONV_DIM) {
          raw[(size_t)row * CONV_DIM + (col - D_INNER)] = __float2bfloat16(v);
        } else if (col < D_IN_PROJ) {
          dtraw[(size_t)row * NHEADS + (col - D_INNER - CONV_DIM)] = v;
        }
      }
    }
}

// ---------------- GEMM2: out = normed @ W_out ----------------
__global__ __launch_bounds__(256) void gemm2_mfma(
    const short* __restrict__ A, const short* __restrict__ Bt,
    float* __restrict__ C) {
  __shared__ short As[128][64];
  __shared__ short Bs[128][64];
  f32x4 acc[4][4] = {};
  const int rowBase = blockIdx.y * 128;
  const int colBase = blockIdx.x * 128;
  mfma_gemm_core(A, Bt, D_INNER, rowBase, colBase, As, Bs, acc);
  const int lane = threadIdx.x & 63, wid = threadIdx.x >> 6;
  const int wr = (wid >> 1) * 64, wc = (wid & 1) * 64;
  const int r0 = rowBase + wr + (lane >> 4) * 4;
  const int cb = colBase + wc + (lane & 15);
#pragma unroll
  for (int m = 0; m < 4; ++m)
#pragma unroll
    for (int n = 0; n < 4; ++n) {
      int col = cb + n * 16;
#pragma unroll
      for (int j = 0; j < 4; ++j)
        C[(size_t)(r0 + m * 16 + j) * D_MODEL + col] = acc[m][n][j];
    }
}

// ---------------- conv1d (depthwise causal, DCONV=4) + SiLU ----------------
__global__ __launch_bounds__(256) void conv_silu_kernel(
    const bf16* __restrict__ raw, const float* __restrict__ cw,
    const float* __restrict__ cb, bf16* __restrict__ conv) {
  size_t idx = (size_t)blockIdx.x * blockDim.x + threadIdx.x;
  if (idx >= (size_t)SEQLEN * CONV_DIM) return;
  int t = (int)(idx / CONV_DIM);
  int c = (int)(idx % CONV_DIM);
  float acc = cb[c];
#pragma unroll
  for (int k = 0; k < DCONV; ++k) {
    int tt = t - (DCONV - 1) + k;
    if (tt >= 0) acc += __bfloat162float(raw[(size_t)tt * CONV_DIM + c]) * cw[c * DCONV + k];
  }
  float s = acc / (1.f + expf(-acc));
  conv[idx] = __float2bfloat16(s);
}

// ---------------- dt softplus (in-place) ----------------
__global__ __launch_bounds__(256) void dt_softplus_kernel(
    float* __restrict__ dtp, const float* __restrict__ dt_bias) {
  int idx = blockIdx.x * blockDim.x + threadIdx.x;
  if (idx >= SEQLEN * NHEADS) return;
  int h = idx & (NHEADS - 1);
  float x = dtp[idx] + dt_bias[h];
  dtp[idx] = (x > 20.f) ? x : log1pf(expf(x));
}

// ---------------- SSD pass A ----------------
__global__ __launch_bounds__(256) void ssd_passA(
    const bf16* __restrict__ conv, const float* __restrict__ dtp,
    const float* __restrict__ A_log, float* __restrict__ Sbuf,
    float* __restrict__ cdec) {
  const int chunk = blockIdx.x;
  const int h = blockIdx.y;
  const int g = h >> 2;
  const int tid = threadIdx.x;
  const int t0 = chunk * CHUNK;
  __shared__ float sdt[CHUNK];
  __shared__ float scum[CHUNK];
  __shared__ float sB[32][64];
  __shared__ float sX[32][64];
  if (tid < CHUNK) sdt[tid] = dtp[(size_t)(t0 + tid) * NHEADS + h];
  __syncthreads();
  if (tid == 0) {
    float Ah = -expf(A_log[h]);
    float run = 0.f;
    for (int i = 0; i < CHUNK; ++i) { run += sdt[i] * Ah; scum[i] = run; }
  }
  __syncthreads();
  const float cumlast = scum[CHUNK - 1];
  const int n = tid >> 2;
  const int p0 = (tid & 3) * 16;
  float acc[16] = {};
  for (int jt = 0; jt < CHUNK; jt += 32) {
    for (int i = tid; i < 32 * 64; i += 256) {
      int r = i >> 6, cc = i & 63;
      size_t trow = (size_t)(t0 + jt + r) * CONV_DIM;
      sB[r][cc] = __bfloat162float(conv[trow + D_XB + g * 64 + cc]);
      sX[r][cc] = __bfloat162float(conv[trow + g * 64 + cc]);
    }
    __syncthreads();
#pragma unroll 4
    for (int r = 0; r < 32; ++r) {
      int j = jt + r;
      float w = expf(cumlast - scum[j]) * sdt[j];
      float bw = sB[r][n] * w;
#pragma unroll
      for (int q = 0; q < 16; ++q) acc[q] += bw * sX[r][p0 + q];
    }
    __syncthreads();
  }
  float* Sout = Sbuf + ((size_t)chunk * NHEADS + h) * (DSTATE * DSTATE);
#pragma unroll
  for (int q = 0; q < 16; ++q) Sout[n * 64 + p0 + q] = acc[q];
  if (tid == 0) cdec[chunk * NHEADS + h] = expf(cumlast);
}

// ---------------- SSD pass B: in-place S -> Hprev ----------------
__global__ __launch_bounds__(256) void ssd_passB(
    float* __restrict__ Sbuf, const float* __restrict__ cdec) {
  const int h = blockIdx.x;
  const int tid = threadIdx.x;
  float H[16] = {};
  for (int c = 0; c < NCHUNK; ++c) {
    float* Sc = Sbuf + ((size_t)c * NHEADS + h) * (DSTATE * DSTATE);
    float dec = cdec[c * NHEADS + h];
#pragma unroll
    for (int q = 0; q < 16; ++q) {
      int e = q * 256 + tid;
      float s = Sc[e];
      Sc[e] = H[q];
      H[q] = dec * H[q] + s;
    }
  }
}

// ---------------- SSD pass C ----------------
__global__ __launch_bounds__(256) void ssd_passC(
    const bf16* __restrict__ z, const bf16* __restrict__ conv,
    const float* __restrict__ dtp, const float* __restrict__ A_log,
    const float* __restrict__ Dv, const float* __restrict__ nw,
    const float* __restrict__ Hprev, bf16* __restrict__ normed) {
  const int chunk = blockIdx.x;
  const int h = blockIdx.y;
  const int g = h >> 2;
  const int tid = threadIdx.x;
  const int t0 = chunk * CHUNK;
  __shared__ float sdt[CHUNK];
  __shared__ float scum[CHUNK];
  __shared__ float sC[CHUNK][64];
  __shared__ float sBX[2][32][64];
  for (int i = tid; i < CHUNK * 64; i += 256) {
    int r = i >> 6, cc = i & 63;
    sC[r][cc] = __bfloat162float(conv[(size_t)(t0 + r) * CONV_DIM + 2 * D_XB + h * 64 + cc]);
  }
  if (tid < CHUNK) sdt[tid] = dtp[(size_t)(t0 + tid) * NHEADS + h];
  __syncthreads();
  if (tid == 0) {
    float Ah = -expf(A_log[h]);
    float run = 0.f;
    for (int i = 0; i < CHUNK; ++i) { run += sdt[i] * Ah; scum[i] = run; }
  }
  __syncthreads();
  const int row = tid >> 1;
  const int p0 = (tid & 1) * 32;
  const float cum_i = scum[row];
  float acc[32] = {};
  for (int jt = 0; jt < CHUNK; jt += 32) {
    for (int i = tid; i < 32 * 64; i += 256) {
      int r = i >> 6, cc = i & 63;
      size_t trow = (size_t)(t0 + jt + r) * CONV_DIM;
      sBX[0][r][cc] = __bfloat162float(conv[trow + D_XB + g * 64 + cc]);
      sBX[1][r][cc] = __bfloat162float(conv[trow + g * 64 + cc]);
    }
    __syncthreads();
    for (int r = 0; r < 32; ++r) {
      int j = jt + r;
      if (j <= row) {
        float gdot = 0.f;
#pragma unroll 8
        for (int n = 0; n < 64; ++n) gdot += sC[row][n] * sBX[0][r][n];
        float w = expf(cum_i - scum[j]) * sdt[j] * gdot;
#pragma unroll
        for (int q = 0; q < 32; ++q) acc[q] += w * sBX[1][r][p0 + q];
      }
    }
    __syncthreads();
  }
  {
    float* sH = &sBX[0][0][0];
    const float* Hp = Hprev + ((size_t)chunk * NHEADS + h) * (DSTATE * DSTATE);
    for (int i = tid; i < DSTATE * DSTATE; i += 256) sH[i] = Hp[i];
    __syncthreads();
    float ecum = expf(cum_i);
#pragma unroll 8
    for (int n = 0; n < 64; ++n) {
      float cn = sC[row][n] * ecum;
#pragma unroll
      for (int q = 0; q < 32; ++q) acc[q] += cn * sH[n * 64 + p0 + q];
    }
  }
  {
    const int t = t0 + row;
    const float Dh = Dv[h];
    float yz[32];
    float sumsq = 0.f;
#pragma unroll
    for (int q = 0; q < 32; ++q) {
      int p = p0 + q;
      float xv = __bfloat162float(conv[(size_t)t * CONV_DIM + g * 64 + p]);
      float zv = __bfloat162float(z[(size_t)t * D_INNER + h * 64 + p]);
      float sz = zv / (1.f + expf(-zv));
      float v = (acc[q] + xv * Dh) * sz;
      yz[q] = v;
      sumsq += v * v;
    }
    sumsq += __shfl_xor(sumsq, 1);
    float rinv = rsqrtf(sumsq * (1.f / 64.f) + EPS);
#pragma unroll
    for (int q = 0; q < 32; ++q) {
      int p = p0 + q;
      normed[(size_t)t * D_INNER + h * 64 + p] = __float2bfloat16(yz[q] * rinv * nw[h * 64 + p]);
    }
  }
}

// ---------------- launch ----------------
extern "C" void kernel_launch(void* const* d_in, const int* in_sizes, int n_in,
                              void* d_out, int out_size, void* d_ws, size_t ws_size,
                              hipStream_t stream) {
  const float* u       = (const float*)d_in[0];
  const float* W_in    = (const float*)d_in[1];
  const float* conv_w  = (const float*)d_in[2];
  const float* conv_b  = (const float*)d_in[3];
  const float* dt_bias = (const float*)d_in[4];
  const float* A_log   = (const float*)d_in[5];
  const float* Dv      = (const float*)d_in[6];
  const float* norm_w  = (const float*)d_in[7];
  const float* W_out   = (const float*)d_in[8];
  float* out = (float*)d_out;

  if (ws_size < WS_BYTES) {
    size_t n = (size_t)out_size;
    fill_kernel<<<(n + 255) / 256, 256, 0, stream>>>(out, n, 1000.0f);
    return;
  }

  char* wsb   = (char*)d_ws;
  bf16*  z    = (bf16*)(wsb);
  bf16*  raw  = (bf16*)(wsb + Z_BYTES);
  float* dtp  = (float*)(wsb + Z_BYTES + RAW_BYTES);
  float* cdec = (float*)(wsb + Z_BYTES + RAW_BYTES + DTP_BYTES);
  char*  R    = wsb + Z_BYTES + RAW_BYTES + DTP_BYTES + CDEC_BYTES;
  // R region aliases: {u_bf16, W_inT} during GEMM1 -> {conv, S} after -> {W_outT} after passC
  short* u_bf  = (short*)(R);
  short* WinT  = (short*)(R + U_BYTES);
  bf16*  conv  = (bf16*)(R);
  float* Sbuf  = (float*)(R + CONV_BYTES);
  short* WoutT = (short*)(R);
  bf16*  normed = raw;   // raw dead after conv

  // 0) casts for GEMM1
  cast_f32_bf16<<<(U_BYTES / 8 + 255) / 256, 256, 0, stream>>>(u, u_bf, U_BYTES / 8);
  {
    dim3 grid(NPAD / 32, D_MODEL / 32);
    transpose_cast<<<grid, 256, 0, stream>>>(W_in, WinT, D_MODEL, D_IN_PROJ);
  }
  // 1) GEMM1 (MFMA)
  {
    dim3 grid(NPAD / 128, SEQLEN / 128);
    gemm1_mfma<<<grid, 256, 0, stream>>>(u_bf, WinT, z, raw, dtp);
  }
  // 2) conv + silu   (overwrites u_bf/WinT region start)
  {
    size_t tot = (size_t)SEQLEN * CONV_DIM;
    conv_silu_kernel<<<(tot + 255) / 256, 256, 0, stream>>>(raw, conv_w, conv_b, conv);
  }
  // 3) dt softplus
  dt_softplus_kernel<<<(SEQLEN * NHEADS + 255) / 256, 256, 0, stream>>>(dtp, dt_bias);
  // 4) SSD pass A
  {
    dim3 grid(NCHUNK, NHEADS);
    ssd_passA<<<grid, 256, 0, stream>>>(conv, dtp, A_log, Sbuf, cdec);
  }
  // 5) SSD pass B
  ssd_passB<<<NHEADS, 256, 0, stream>>>(Sbuf, cdec);
  // 6) SSD pass C -> normed (aliases raw)
  {
    dim3 grid(NCHUNK, NHEADS);
    ssd_passC<<<grid, 256, 0, stream>>>(z, conv, dtp, A_log, Dv, norm_w, Sbuf, normed);
  }
  // 7) cast W_out (overwrites conv region, dead now) + GEMM2 (MFMA)
  {
    dim3 grid(D_MODEL / 32, D_INNER / 32);
    transpose_cast<<<grid, 256, 0, stream>>>(W_out, WoutT, D_INNER, D_MODEL);
  }
  {
    dim3 grid(D_MODEL / 128, SEQLEN / 128);
    gemm2_mfma<<<grid, 256, 0, stream>>>((const short*)normed, WoutT, out);
  }
}

// Round 4
// 664.905 us; speedup vs baseline: 9.5689x; 2.0868x over previous
//
#include <hip/hip_runtime.h>
#include <hip/hip_bf16.h>
#include <math.h>

typedef __hip_bfloat16 bf16;
typedef __attribute__((ext_vector_type(8))) short short8;
typedef __attribute__((ext_vector_type(4))) float f32x4;

#define D_MODEL   2048
#define D_INNER   4096
#define NHEADS    64
#define DSTATE    64
#define D_XB      1024
#define XB_HEADS  16
#define REP       4
#define DCONV     4
#define CHUNK     128
#define SEQLEN    4096
#define NCHUNK    (SEQLEN / CHUNK)                 // 32
#define D_IN_PROJ (2*D_INNER + 2*D_XB + NHEADS)    // 10304
#define NPAD      10368                            // 81*128
#define CONV_DIM  (D_INNER + 2*D_XB)               // 6144
#define EPS       1e-5f
#define LOG2E     1.44269504f

// ---------------- workspace layout (bytes) ----------------
#define Z_BYTES    ((size_t)SEQLEN * D_INNER * 2)                   // 33,554,432
#define RAW_BYTES  ((size_t)SEQLEN * CONV_DIM * 2)                  // 50,331,648
#define DTP_BYTES  ((size_t)SEQLEN * NHEADS * 4)                    //  1,048,576
#define CDEC_BYTES ((size_t)NCHUNK * NHEADS * 4)                    //      8,192
#define CONV_BYTES ((size_t)SEQLEN * CONV_DIM * 2)                  // 50,331,648
#define S_BYTES    ((size_t)NCHUNK * NHEADS * DSTATE * DSTATE * 4)  // 33,554,432 (use half as bf16)
#define U_BYTES    ((size_t)SEQLEN * D_MODEL * 2)
#define RREG_BYTES (CONV_BYTES + S_BYTES)                           // 83,886,080 (>= U+WinT)
#define WS_BYTES   (Z_BYTES + RAW_BYTES + DTP_BYTES + CDEC_BYTES + RREG_BYTES)

__device__ __forceinline__ short f2bf(float f) {
  bf16 h = __float2bfloat16(f);
  return *reinterpret_cast<short*>(&h);
}
__device__ __forceinline__ float bf2f(short s) {
  unsigned int u = ((unsigned int)(unsigned short)s) << 16;
  union { unsigned int u; float f; } c; c.u = u; return c.f;
}

__device__ __forceinline__ void gload_lds16(const void* g, void* l) {
  typedef __attribute__((address_space(1))) const unsigned int guint;
  typedef __attribute__((address_space(3))) unsigned int luint;
  __builtin_amdgcn_global_load_lds((guint*)g, (luint*)l, 16, 0, 0);
}

// swizzled LDS addressing: 64-elem bf16 rows (128 B) and 128-elem rows (256 B)
__device__ __forceinline__ char* swz128p(char* b, int r, int c) {
  int o = r * 128 + c * 2; o ^= (r & 7) << 4; return b + o;
}
__device__ __forceinline__ const char* swz128p(const char* b, int r, int c) {
  int o = r * 128 + c * 2; o ^= (r & 7) << 4; return b + o;
}
__device__ __forceinline__ char* swz256p(char* b, int r, int c) {
  int o = r * 256 + c * 2; o ^= (r & 15) << 4; return b + o;
}
__device__ __forceinline__ const char* swz256p(const char* b, int r, int c) {
  int o = r * 256 + c * 2; o ^= (r & 15) << 4; return b + o;
}

// ---------------- diagnostic fill ----------------
__global__ void fill_kernel(float* p, size_t n, float v) {
  size_t i = (size_t)blockIdx.x * blockDim.x + threadIdx.x;
  if (i < n) p[i] = v;
}

// ---------------- cast f32 -> bf16 ----------------
__global__ __launch_bounds__(256) void cast_f32_bf16(
    const float* __restrict__ in, short* __restrict__ out, size_t n4) {
  size_t i = (size_t)blockIdx.x * 256 + threadIdx.x;
  if (i >= n4) return;
  float4 v = ((const float4*)in)[i];
  short4 o;
  o.x = f2bf(v.x); o.y = f2bf(v.y); o.z = f2bf(v.z); o.w = f2bf(v.w);
  ((short4*)out)[i] = o;
}

// ---------------- transpose + cast: in[R][C] f32 -> out[Cpad][R] bf16 ----------------
__global__ __launch_bounds__(256) void transpose_cast(
    const float* __restrict__ in, short* __restrict__ out, int R, int C) {
  __shared__ float tile[32][33];
  const int c0 = blockIdx.x * 32;
  const int r0 = blockIdx.y * 32;
  const int tx = threadIdx.x & 31, ty = threadIdx.x >> 5;
#pragma unroll
  for (int i = 0; i < 4; ++i) {
    int r = ty + i * 8;
    float v = 0.f;
    if (c0 + tx < C) v = in[(size_t)(r0 + r) * C + c0 + tx];
    tile[r][tx] = v;
  }
  __syncthreads();
#pragma unroll
  for (int i = 0; i < 4; ++i) {
    int rr = ty + i * 8;
    out[(size_t)(c0 + rr) * R + r0 + tx] = f2bf(tile[tx][rr]);
  }
}

// ---------------- MFMA GEMM core: 128x128 tile, BK=64, 4 waves ----------------
__device__ __forceinline__ void mfma_gemm_core(
    const short* __restrict__ A, const short* __restrict__ Bt, int K,
    int rowBase, int colBase, short As[128][64], short Bs[128][64],
    f32x4 acc[4][4]) {
  const int tid = threadIdx.x;
  const int lane = tid & 63;
  const int wid = tid >> 6;
  const int r_sub = lane >> 3;
  const int c8 = (lane & 7) * 8;
  const int wr = (wid >> 1) * 64;
  const int wc = (wid & 1) * 64;
  const int fr = lane & 15;
  const int kb = (lane >> 4) * 8;
  for (int k0 = 0; k0 < K; k0 += 64) {
#pragma unroll
    for (int i = 0; i < 4; ++i) {
      int c = i * 4 + wid;
      int r = c * 8 + r_sub;
      gload_lds16(A + (size_t)(rowBase + r) * K + k0 + c8, &As[r][c8]);
      gload_lds16(Bt + (size_t)(colBase + r) * K + k0 + c8, &Bs[r][c8]);
    }
    __syncthreads();
#pragma unroll
    for (int kk = 0; kk < 2; ++kk) {
      const int ko = kk * 32 + kb;
      short8 a[4], b[4];
#pragma unroll
      for (int m = 0; m < 4; ++m) a[m] = *(const short8*)&As[wr + m * 16 + fr][ko];
#pragma unroll
      for (int n = 0; n < 4; ++n) b[n] = *(const short8*)&Bs[wc + n * 16 + fr][ko];
#pragma unroll
      for (int m = 0; m < 4; ++m)
#pragma unroll
        for (int n = 0; n < 4; ++n)
          acc[m][n] = __builtin_amdgcn_mfma_f32_16x16x32_bf16(a[m], b[n], acc[m][n], 0, 0, 0);
    }
    __syncthreads();
  }
}

// ---------------- GEMM1 ----------------
__global__ __launch_bounds__(256) void gemm1_mfma(
    const short* __restrict__ A, const short* __restrict__ Bt,
    bf16* __restrict__ z, bf16* __restrict__ raw, float* __restrict__ dtraw) {
  __shared__ short As[128][64];
  __shared__ short Bs[128][64];
  f32x4 acc[4][4] = {};
  const int rowBase = blockIdx.y * 128;
  const int colBase = blockIdx.x * 128;
  mfma_gemm_core(A, Bt, D_MODEL, rowBase, colBase, As, Bs, acc);
  const int lane = threadIdx.x & 63, wid = threadIdx.x >> 6;
  const int wr = (wid >> 1) * 64, wc = (wid & 1) * 64;
  const int r0 = rowBase + wr + (lane >> 4) * 4;
  const int cb = colBase + wc + (lane & 15);
#pragma unroll
  for (int m = 0; m < 4; ++m)
#pragma unroll
    for (int n = 0; n < 4; ++n) {
      int col = cb + n * 16;
#pragma unroll
      for (int j = 0; j < 4; ++j) {
        int row = r0 + m * 16 + j;
        float v = acc[m][n][j];
        if (col < D_INNER) {
          z[(size_t)row * D_INNER + col] = __float2bfloat16(v);
        } else if (col < D_INNER + CONV_DIM) {
          raw[(size_t)row * CONV_DIM + (col - D_INNER)] = __float2bfloat16(v);
        } else if (col < D_IN_PROJ) {
          dtraw[(size_t)row * NHEADS + (col - D_INNER - CONV_DIM)] = v;
        }
      }
    }
}

// ---------------- GEMM2 ----------------
__global__ __launch_bounds__(256) void gemm2_mfma(
    const short* __restrict__ A, const short* __restrict__ Bt,
    float* __restrict__ C) {
  __shared__ short As[128][64];
  __shared__ short Bs[128][64];
  f32x4 acc[4][4] = {};
  const int rowBase = blockIdx.y * 128;
  const int colBase = blockIdx.x * 128;
  mfma_gemm_core(A, Bt, D_INNER, rowBase, colBase, As, Bs, acc);
  const int lane = threadIdx.x & 63, wid = threadIdx.x >> 6;
  const int wr = (wid >> 1) * 64, wc = (wid & 1) * 64;
  const int r0 = rowBase + wr + (lane >> 4) * 4;
  const int cb = colBase + wc + (lane & 15);
#pragma unroll
  for (int m = 0; m < 4; ++m)
#pragma unroll
    for (int n = 0; n < 4; ++n) {
      int col = cb + n * 16;
#pragma unroll
      for (int j = 0; j < 4; ++j)
        C[(size_t)(r0 + m * 16 + j) * D_MODEL + col] = acc[m][n][j];
    }
}

// ---------------- conv1d + SiLU ----------------
__global__ __launch_bounds__(256) void conv_silu_kernel(
    const bf16* __restrict__ raw, const float* __restrict__ cw,
    const float* __restrict__ cb, bf16* __restrict__ convout) {
  size_t idx = (size_t)blockIdx.x * blockDim.x + threadIdx.x;
  if (idx >= (size_t)SEQLEN * CONV_DIM) return;
  int t = (int)(idx / CONV_DIM);
  int c = (int)(idx % CONV_DIM);
  float acc = cb[c];
#pragma unroll
  for (int k = 0; k < DCONV; ++k) {
    int tt = t - (DCONV - 1) + k;
    if (tt >= 0) acc += __bfloat162float(raw[(size_t)tt * CONV_DIM + c]) * cw[c * DCONV + k];
  }
  float s = acc / (1.f + expf(-acc));
  convout[idx] = __float2bfloat16(s);
}

// ---------------- dt softplus ----------------
__global__ __launch_bounds__(256) void dt_softplus_kernel(
    float* __restrict__ dtp, const float* __restrict__ dt_bias) {
  int idx = blockIdx.x * blockDim.x + threadIdx.x;
  if (idx >= SEQLEN * NHEADS) return;
  int h = idx & (NHEADS - 1);
  float x = dtp[idx] + dt_bias[h];
  dtp[idx] = (x > 20.f) ? x : log1pf(expf(x));
}

// ---------------- SSD pass A (MFMA): ST[p][n] = sum_j X[j,p]*w_j*B[j,n] ----------------
__global__ __launch_bounds__(256) void ssd_passA(
    const bf16* __restrict__ conv, const float* __restrict__ dtp,
    const float* __restrict__ A_log, short* __restrict__ Sbuf,
    float* __restrict__ cdec) {
  __shared__ __align__(16) char sBn[16384];
  __shared__ __align__(16) char sXn[16384];
  __shared__ __align__(16) char sBT[16384];
  __shared__ __align__(16) char sXT[16384];
  __shared__ float sdt[CHUNK], scum2[CHUNK], sw[CHUNK];
  const int chunk = blockIdx.x, h = blockIdx.y, g = h >> 2;
  const int tid = threadIdx.x, lane = tid & 63, wid = tid >> 6;
  const int t0 = chunk * CHUNK;
  const int fr = lane & 15, kq = lane >> 4;
  // stage B, X (normal layout, swizzled)
  {
    const short* cg = (const short*)conv;
#pragma unroll
    for (int it = 0; it < 4; ++it) {
      int cid = tid + it * 256;
      int r = cid >> 3, c8 = (cid & 7) * 8;
      size_t rowoff = (size_t)(t0 + r) * CONV_DIM;
      *(short8*)swz128p(sBn, r, c8) = *(const short8*)(cg + rowoff + D_XB + g * 64 + c8);
      *(short8*)swz128p(sXn, r, c8) = *(const short8*)(cg + rowoff + g * 64 + c8);
    }
    if (tid < CHUNK) sdt[tid] = dtp[(size_t)(t0 + tid) * NHEADS + h];
  }
  __syncthreads();
  // cumulative decay (log2 domain) + per-j weights
  if (tid < CHUNK) {
    float Ah2 = -expf(A_log[h]) * LOG2E;
    float s_all = 0.f, s_le = 0.f;
    for (int i = 0; i < CHUNK; ++i) {
      float v = sdt[i] * Ah2;
      s_all += v;
      if (i <= tid) s_le += v;
    }
    scum2[tid] = s_le;
    sw[tid] = exp2f(s_all - s_le) * sdt[tid];
    if (tid == 0) cdec[chunk * NHEADS + h] = exp2f(s_all);
  }
  __syncthreads();
  // transpose: BT[n][j] = B[j][n]; XT[p][j] = X[j][p]*w_j
  {
    const int col = tid & 63, jb = (tid >> 6) * 32;
#pragma unroll
    for (int it = 0; it < 32; ++it) {
      int j = jb + it;
      *(short*)swz256p(sBT, col, j) = *(const short*)swz128p(sBn, j, col);
      float xv = bf2f(*(const short*)swz128p(sXn, j, col));
      *(short*)swz256p(sXT, col, j) = f2bf(xv * sw[j]);
    }
  }
  __syncthreads();
  // MFMA: M=64(p) N=64(n) K=128(j); each wave 16 rows
  f32x4 acc[4] = {};
#pragma unroll
  for (int ks = 0; ks < 4; ++ks) {
    short8 a = *(const short8*)swz256p(sXT, wid * 16 + fr, ks * 32 + kq * 8);
    short8 b[4];
#pragma unroll
    for (int n = 0; n < 4; ++n) b[n] = *(const short8*)swz256p(sBT, n * 16 + fr, ks * 32 + kq * 8);
#pragma unroll
    for (int n = 0; n < 4; ++n)
      acc[n] = __builtin_amdgcn_mfma_f32_16x16x32_bf16(a, b[n], acc[n], 0, 0, 0);
  }
  short* So = Sbuf + ((size_t)(chunk * NHEADS + h)) * (DSTATE * DSTATE);
#pragma unroll
  for (int n = 0; n < 4; ++n)
#pragma unroll
    for (int jj = 0; jj < 4; ++jj) {
      int p = wid * 16 + kq * 4 + jj;
      int nc = n * 16 + fr;
      So[p * 64 + nc] = f2bf(acc[n][jj]);
    }
}

// ---------------- SSD pass B: recurrence, in-place S->Hprev (bf16) ----------------
__global__ __launch_bounds__(256) void ssd_passB(
    short* __restrict__ Sbuf, const float* __restrict__ cdec) {
  const int h = blockIdx.x;
  const int base = blockIdx.y * 1024 + threadIdx.x * 4;
  float H[4] = {};
  for (int c = 0; c < NCHUNK; ++c) {
    short4* Sc = (short4*)(Sbuf + ((size_t)(c * NHEADS + h)) * (DSTATE * DSTATE) + base);
    short4 v = *Sc;
    short4 o;
    o.x = f2bf(H[0]); o.y = f2bf(H[1]); o.z = f2bf(H[2]); o.w = f2bf(H[3]);
    *Sc = o;
    float dec = cdec[c * NHEADS + h];
    H[0] = dec * H[0] + bf2f(v.x);
    H[1] = dec * H[1] + bf2f(v.y);
    H[2] = dec * H[2] + bf2f(v.z);
    H[3] = dec * H[3] + bf2f(v.w);
  }
}

// ---------------- SSD pass C (MFMA) ----------------
__global__ __launch_bounds__(256) void ssd_passC(
    const bf16* __restrict__ z, const bf16* __restrict__ conv,
    const float* __restrict__ dtp, const float* __restrict__ A_log,
    const float* __restrict__ Dv, const float* __restrict__ nw,
    const short* __restrict__ Hprev, bf16* __restrict__ normed) {
  __shared__ __align__(16) char sC[16384];    // C tile [128][64] swz128
  __shared__ __align__(16) char sBX[16384];   // B tile [128][64] swz128, then XT [64][128] swz256
  __shared__ __align__(16) char sP[32768];    // upper 16K: Xn [128][64]; later P [128][128] swz256
  __shared__ __align__(16) char sST[8192];    // Hprev tile [64][64] swz128
  __shared__ float sdt[CHUNK], scum2[CHUNK];
  const int chunk = blockIdx.x, h = blockIdx.y, g = h >> 2;
  const int tid = threadIdx.x, lane = tid & 63, wid = tid >> 6;
  const int t0 = chunk * CHUNK;
  const int fr = lane & 15, kq = lane >> 4;
  const int wi = wid * 32;
  // phase 1: stage C, B, Xn, dt
  {
    const short* cg = (const short*)conv;
#pragma unroll
    for (int it = 0; it < 4; ++it) {
      int cid = tid + it * 256;
      int r = cid >> 3, c8 = (cid & 7) * 8;
      size_t rowoff = (size_t)(t0 + r) * CONV_DIM;
      *(short8*)swz128p(sC, r, c8) = *(const short8*)(cg + rowoff + 2 * D_XB + h * 64 + c8);
      *(short8*)swz128p(sBX, r, c8) = *(const short8*)(cg + rowoff + D_XB + g * 64 + c8);
      *(short8*)swz128p(sP + 16384, r, c8) = *(const short8*)(cg + rowoff + g * 64 + c8);
    }
    if (tid < CHUNK) sdt[tid] = dtp[(size_t)(t0 + tid) * NHEADS + h];
  }
  __syncthreads();
  // phase 2: cum (log2 domain)
  if (tid < CHUNK) {
    float Ah2 = -expf(A_log[h]) * LOG2E;
    float s_le = 0.f;
    for (int i = 0; i <= tid; ++i) s_le += sdt[i] * Ah2;
    scum2[tid] = s_le;
  }
  __syncthreads();
  // phase 3: G = C @ B^T  (each wave: 32 i-rows x 128 j)
  f32x4 accG[2][8] = {};
#pragma unroll
  for (int ks = 0; ks < 2; ++ks) {
    short8 a[2], b[8];
#pragma unroll
    for (int m = 0; m < 2; ++m)
      a[m] = *(const short8*)swz128p(sC, wi + m * 16 + fr, ks * 32 + kq * 8);
#pragma unroll
    for (int n = 0; n < 8; ++n)
      b[n] = *(const short8*)swz128p(sBX, n * 16 + fr, ks * 32 + kq * 8);
#pragma unroll
    for (int m = 0; m < 2; ++m)
#pragma unroll
      for (int n = 0; n < 8; ++n)
        accG[m][n] = __builtin_amdgcn_mfma_f32_16x16x32_bf16(a[m], b[n], accG[m][n], 0, 0, 0);
  }
  __syncthreads();
  // phase 4: transpose Xn -> XT (into sBX); stage Hprev -> sST
  {
    const int p = tid & 63, jb = (tid >> 6) * 32;
#pragma unroll
    for (int it = 0; it < 32; ++it) {
      int j = jb + it;
      *(short*)swz256p(sBX, p, j) = *(const short*)swz128p(sP + 16384, j, p);
    }
    const short* Hp = Hprev + ((size_t)(chunk * NHEADS + h)) * (DSTATE * DSTATE);
#pragma unroll
    for (int it = 0; it < 2; ++it) {
      int cid = tid + it * 256;
      int pr = cid >> 3, c8 = (cid & 7) * 8;
      *(short8*)swz128p(sST, pr, c8) = *(const short8*)(Hp + pr * 64 + c8);
    }
  }
  __syncthreads();
  // phase 5: P = mask(G) -> bf16 in sP
#pragma unroll
  for (int m = 0; m < 2; ++m)
#pragma unroll
    for (int jj = 0; jj < 4; ++jj) {
      int i = wi + m * 16 + kq * 4 + jj;
      float ci = scum2[i];
#pragma unroll
      for (int n = 0; n < 8; ++n) {
        int j = n * 16 + fr;
        float w = (j <= i) ? exp2f(ci - scum2[j]) * sdt[j] : 0.f;
        *(short*)swz256p(sP, i, j) = f2bf(accG[m][n][jj] * w);
      }
    }
  __syncthreads();
  // phase 6: Y = P @ XT  +  exp(cum_i) * (C @ ST)
  f32x4 acc1[2][4] = {};
#pragma unroll
  for (int ks = 0; ks < 4; ++ks) {
    short8 a[2], b[4];
#pragma unroll
    for (int m = 0; m < 2; ++m)
      a[m] = *(const short8*)swz256p(sP, wi + m * 16 + fr, ks * 32 + kq * 8);
#pragma unroll
    for (int n = 0; n < 4; ++n)
      b[n] = *(const short8*)swz256p(sBX, n * 16 + fr, ks * 32 + kq * 8);
#pragma unroll
    for (int m = 0; m < 2; ++m)
#pragma unroll
      for (int n = 0; n < 4; ++n)
        acc1[m][n] = __builtin_amdgcn_mfma_f32_16x16x32_bf16(a[m], b[n], acc1[m][n], 0, 0, 0);
  }
  f32x4 acc2[2][4] = {};
#pragma unroll
  for (int ks = 0; ks < 2; ++ks) {
    short8 a[2], b[4];
#pragma unroll
    for (int m = 0; m < 2; ++m)
      a[m] = *(const short8*)swz128p(sC, wi + m * 16 + fr, ks * 32 + kq * 8);
#pragma unroll
    for (int n = 0; n < 4; ++n)
      b[n] = *(const short8*)swz128p(sST, n * 16 + fr, ks * 32 + kq * 8);
#pragma unroll
    for (int m = 0; m < 2; ++m)
#pragma unroll
      for (int n = 0; n < 4; ++n)
        acc2[m][n] = __builtin_amdgcn_mfma_f32_16x16x32_bf16(a[m], b[n], acc2[m][n], 0, 0, 0);
  }
  // epilogue: +x*D, gate silu(z), RMSNorm, write normed
  const float Dh = Dv[h];
#pragma unroll
  for (int m = 0; m < 2; ++m)
#pragma unroll
    for (int jj = 0; jj < 4; ++jj) {
      int i = wi + m * 16 + kq * 4 + jj;
      int t = t0 + i;
      float e2 = exp2f(scum2[i]);
      float vs[4];
      float ss = 0.f;
#pragma unroll
      for (int n = 0; n < 4; ++n) {
        int p = n * 16 + fr;
        float xv = bf2f(((const short*)conv)[(size_t)t * CONV_DIM + g * 64 + p]);
        float zv = bf2f(((const short*)z)[(size_t)t * D_INNER + h * 64 + p]);
        float y = acc1[m][n][jj] + e2 * acc2[m][n][jj] + xv * Dh;
        float sz = zv / (1.f + expf(-zv));
        float v = y * sz;
        vs[n] = v;
        ss += v * v;
      }
      ss += __shfl_xor(ss, 1);
      ss += __shfl_xor(ss, 2);
      ss += __shfl_xor(ss, 4);
      ss += __shfl_xor(ss, 8);
      float rinv = rsqrtf(ss * (1.f / 64.f) + EPS);
#pragma unroll
      for (int n = 0; n < 4; ++n) {
        int p = n * 16 + fr;
        ((short*)normed)[(size_t)t * D_INNER + h * 64 + p] = f2bf(vs[n] * rinv * nw[h * 64 + p]);
      }
    }
}

// ---------------- launch ----------------
extern "C" void kernel_launch(void* const* d_in, const int* in_sizes, int n_in,
                              void* d_out, int out_size, void* d_ws, size_t ws_size,
                              hipStream_t stream) {
  const float* u       = (const float*)d_in[0];
  const float* W_in    = (const float*)d_in[1];
  const float* conv_w  = (const float*)d_in[2];
  const float* conv_b  = (const float*)d_in[3];
  const float* dt_bias = (const float*)d_in[4];
  const float* A_log   = (const float*)d_in[5];
  const float* Dv      = (const float*)d_in[6];
  const float* norm_w  = (const float*)d_in[7];
  const float* W_out   = (const float*)d_in[8];
  float* out = (float*)d_out;

  if (ws_size < WS_BYTES) {
    size_t n = (size_t)out_size;
    fill_kernel<<<(n + 255) / 256, 256, 0, stream>>>(out, n, 1000.0f);
    return;
  }

  char* wsb   = (char*)d_ws;
  bf16*  z    = (bf16*)(wsb);
  bf16*  raw  = (bf16*)(wsb + Z_BYTES);
  float* dtp  = (float*)(wsb + Z_BYTES + RAW_BYTES);
  float* cdec = (float*)(wsb + Z_BYTES + RAW_BYTES + DTP_BYTES);
  char*  R    = wsb + Z_BYTES + RAW_BYTES + DTP_BYTES + CDEC_BYTES;
  short* u_bf  = (short*)(R);
  short* WinT  = (short*)(R + U_BYTES);
  bf16*  conv  = (bf16*)(R);
  short* Sbuf  = (short*)(R + CONV_BYTES);
  short* WoutT = (short*)(R);
  bf16*  normed = raw;

  // 0) casts for GEMM1
  cast_f32_bf16<<<(U_BYTES / 8 + 255) / 256, 256, 0, stream>>>(u, u_bf, U_BYTES / 8);
  {
    dim3 grid(NPAD / 32, D_MODEL / 32);
    transpose_cast<<<grid, 256, 0, stream>>>(W_in, WinT, D_MODEL, D_IN_PROJ);
  }
  // 1) GEMM1 (MFMA)
  {
    dim3 grid(NPAD / 128, SEQLEN / 128);
    gemm1_mfma<<<grid, 256, 0, stream>>>(u_bf, WinT, z, raw, dtp);
  }
  // 2) conv + silu
  {
    size_t tot = (size_t)SEQLEN * CONV_DIM;
    conv_silu_kernel<<<(tot + 255) / 256, 256, 0, stream>>>(raw, conv_w, conv_b, conv);
  }
  // 3) dt softplus
  dt_softplus_kernel<<<(SEQLEN * NHEADS + 255) / 256, 256, 0, stream>>>(dtp, dt_bias);
  // 4) SSD pass A (MFMA)
  {
    dim3 grid(NCHUNK, NHEADS);
    ssd_passA<<<grid, 256, 0, stream>>>(conv, dtp, A_log, Sbuf, cdec);
  }
  // 5) SSD pass B
  {
    dim3 grid(NHEADS, 4);
    ssd_passB<<<grid, 256, 0, stream>>>(Sbuf, cdec);
  }
  // 6) SSD pass C (MFMA)
  {
    dim3 grid(NCHUNK, NHEADS);
    ssd_passC<<<grid, 256, 0, stream>>>(z, conv, dtp, A_log, Dv, norm_w, Sbuf, normed);
  }
  // 7) W_out transpose + GEMM2 (MFMA)
  {
    dim3 grid(D_MODEL / 32, D_INNER / 32);
    transpose_cast<<<grid, 256, 0, stream>>>(W_out, WoutT, D_INNER, D_MODEL);
  }
  {
    dim3 grid(D_MODEL / 128, SEQLEN / 128);
    gemm2_mfma<<<grid, 256, 0, stream>>>((const short*)normed, WoutT, out);
  }
}